// Round 4
// baseline (302.526 us; speedup 1.0000x reference)
//
#include <hip/hip_runtime.h>

typedef __attribute__((ext_vector_type(8))) short short8;
typedef __attribute__((ext_vector_type(4))) float f32x4;
typedef __attribute__((ext_vector_type(4))) float float4v;
typedef __attribute__((ext_vector_type(8))) float f32x8;
typedef __attribute__((ext_vector_type(4))) unsigned short us4;
typedef __attribute__((ext_vector_type(4))) unsigned int uint4v;

#define DEVI __device__ __forceinline__
#define MFMA16(a,b,c) __builtin_amdgcn_mfma_f32_16x16x32_bf16((a),(b),(c),0,0,0)

// ---------- helpers ----------
DEVI unsigned short f2bf(float x) {            // f32 -> bf16 bits, RNE
    unsigned u = __builtin_bit_cast(unsigned, x);
    u += 0x7FFFu + ((u >> 16) & 1u);
    return (unsigned short)(u >> 16);
}
DEVI float bf2f(unsigned short b) {
    return __builtin_bit_cast(float, ((unsigned)b) << 16);
}

// ---------- prep: split hidden f32 -> bf16 hi/lo ----------
__global__ __launch_bounds__(256) void k_prep_hidden(const float* __restrict__ hid,
                                                     unsigned short* __restrict__ hh,
                                                     unsigned short* __restrict__ hl) {
    int i = blockIdx.x * 256 + threadIdx.x;     // 524288 threads, 4 f32 each
    float4v v = *reinterpret_cast<const float4v*>(hid + (long)i * 4);
    us4 a, b;
    #pragma unroll
    for (int j = 0; j < 4; ++j) {
        float x = v[j];
        unsigned short h = f2bf(x);
        a[j] = h;
        b[j] = f2bf(x - bf2f(h));
    }
    *reinterpret_cast<us4*>(hh + (long)i * 4) = a;
    *reinterpret_cast<us4*>(hl + (long)i * 4) = b;
}

// ---------- prep: transpose weights, split Wq/Wk (R2-proven scalar version) ----------
__global__ __launch_bounds__(256) void k_prep_w(const float* __restrict__ wq, const float* __restrict__ wk,
                                                const float* __restrict__ wv, const float* __restrict__ wo,
                                                unsigned short* wqthi, unsigned short* wqtlo,
                                                unsigned short* wkthi, unsigned short* wktlo,
                                                unsigned short* wvt, unsigned short* wot) {
    int t = blockIdx.x * 256 + threadIdx.x;     // 4*262144 threads
    int which = t >> 18;
    int idx = t & 0x3FFFF;
    int k = idx >> 9, n = idx & 511;
    int o = n * 512 + k;                        // transposed [n][k]
    if (which == 0) {
        float x = wq[idx]; unsigned short h = f2bf(x);
        wqthi[o] = h; wqtlo[o] = f2bf(x - bf2f(h));
    } else if (which == 1) {
        float x = wk[idx]; unsigned short h = f2bf(x);
        wkthi[o] = h; wktlo[o] = f2bf(x - bf2f(h));
    } else if (which == 2) {
        wvt[o] = f2bf(wv[idx]);
    } else {
        wot[o] = f2bf(wo[idx]);
    }
}

// ---------- prep: bias table biasT[h][rel+2047] ----------
DEVI int bucket_large(int a) {   // exact integer thresholds of 8+floor(2*log2(a/8)), clamp 15
    if (a < 12) return 8;
    if (a < 16) return 9;
    if (a < 23) return 10;
    if (a < 32) return 11;
    if (a < 46) return 12;
    if (a < 64) return 13;
    if (a < 91) return 14;
    return 15;
}
__global__ __launch_bounds__(256) void k_prep_bias(const float* __restrict__ emb, float* __restrict__ biasT) {
    int t = blockIdx.x * 256 + threadIdx.x;
    if (t >= 8 * 4095) return;
    int h = t / 4095;
    int idx = t - h * 4095;
    int rel = idx - 2047;                // rel = k - q
    int a = rel < 0 ? -rel : rel;
    int bucket = (rel > 0 ? 16 : 0) + (a < 8 ? a : bucket_large(a));
    biasT[h * 4096 + idx] = emb[bucket * 8 + h];
}

// ---------- fused QKV projection (R2-proven) ----------
__global__ __launch_bounds__(256) void k_proj(const unsigned short* __restrict__ hh,
                                              const unsigned short* __restrict__ hl,
                                              const unsigned short* __restrict__ wqthi, const unsigned short* __restrict__ wqtlo,
                                              const unsigned short* __restrict__ wkthi, const unsigned short* __restrict__ wktlo,
                                              const unsigned short* __restrict__ wvt,
                                              unsigned short* __restrict__ q_hi, unsigned short* __restrict__ q_lo,
                                              unsigned short* __restrict__ k_hi, unsigned short* __restrict__ k_lo,
                                              unsigned short* __restrict__ vT) {
    const int wgid = blockIdx.x;            // 384 = 32 mt * 12 nt
    const int nt = wgid % 12, mt = wgid / 12;
    const int sec = nt >> 2;                // 0:Q 1:K 2:V
    const bool isv = (sec == 2);
    const int tid = threadIdx.x, wv = tid >> 6, lane = tid & 63;
    const int wr = wv >> 1, wc = wv & 1;
    const int g = lane >> 4, li = lane & 15;
    const int m0 = mt * 128 + wr * 64;
    const int n0 = (nt & 3) * 128 + wc * 64;    // col within section [0,512)
    const unsigned short* bh_ = (sec == 0) ? wqthi : (sec == 1) ? wkthi : wvt;
    const unsigned short* bl_ = (sec == 0) ? wqtlo : wktlo;

    f32x4 zf = {0.f, 0.f, 0.f, 0.f};
    f32x4 acc[4][4];
    #pragma unroll
    for (int i = 0; i < 4; ++i)
        #pragma unroll
        for (int j = 0; j < 4; ++j) acc[i][j] = zf;

    for (int ks = 0; ks < 512; ks += 32) {
        int koff = ks + g * 8;
        short8 ah[4], al[4], bhf[4], blf[4];
        #pragma unroll
        for (int i = 0; i < 4; ++i) {
            long ar = (long)(m0 + i * 16 + li) * 512 + koff;
            ah[i] = *reinterpret_cast<const short8*>(hh + ar);
            if (!isv) al[i] = *reinterpret_cast<const short8*>(hl + ar);
            long br = (long)(n0 + i * 16 + li) * 512 + koff;
            bhf[i] = *reinterpret_cast<const short8*>(bh_ + br);
            if (!isv) blf[i] = *reinterpret_cast<const short8*>(bl_ + br);
        }
        #pragma unroll
        for (int i = 0; i < 4; ++i)
            #pragma unroll
            for (int j = 0; j < 4; ++j) {
                acc[i][j] = MFMA16(ah[i], bhf[j], acc[i][j]);
                if (!isv) {
                    acc[i][j] = MFMA16(ah[i], blf[j], acc[i][j]);
                    acc[i][j] = MFMA16(al[i], bhf[j], acc[i][j]);
                }
            }
    }

    if (!isv) {
        unsigned short* ohi = (sec == 0) ? q_hi : k_hi;
        unsigned short* olo = (sec == 0) ? q_lo : k_lo;
        #pragma unroll
        for (int i = 0; i < 4; ++i) {
            int rowb = m0 + i * 16 + g * 4;
            #pragma unroll
            for (int j = 0; j < 4; ++j) {
                int col = n0 + j * 16 + li;
                #pragma unroll
                for (int r = 0; r < 4; ++r) {
                    float x = acc[i][j][r];
                    unsigned short hb = f2bf(x);
                    long o = (long)(rowb + r) * 512 + col;
                    ohi[o] = hb;
                    olo[o] = f2bf(x - bf2f(hb));
                }
            }
        }
    } else {
        #pragma unroll
        for (int i = 0; i < 4; ++i) {
            int rowb = m0 + i * 16 + g * 4;      // 4 consecutive s
            int bb = rowb >> 11, ss = rowb & 2047;
            #pragma unroll
            for (int j = 0; j < 4; ++j) {
                int nv = n0 + j * 16 + li;       // [0,512)
                int hh2 = nv >> 6, dd = nv & 63;
                us4 w;
                #pragma unroll
                for (int r = 0; r < 4; ++r) w[r] = f2bf(acc[i][j][r]);
                *reinterpret_cast<us4*>(vT + ((long)((bb * 8 + hh2) * 64 + dd)) * 2048 + ss) = w;
            }
        }
    }
}

// ---------- flash attention: R2-verbatim inner loop; intra-block k-split x2 ----------
// grid 1024: wg = bh*64 + qb32. 4 waves: qsub = wv&1 (16 q rows each),
// khalf = wv>>1 (k in [0,1024) or [1024,2048)). LDS merge at the end.
__global__ __launch_bounds__(256) void k_attn(const unsigned short* __restrict__ qhi,
                                              const unsigned short* __restrict__ qlo,
                                              const unsigned short* __restrict__ khi,
                                              const unsigned short* __restrict__ klo,
                                              const unsigned short* __restrict__ vT,
                                              const float* __restrict__ biasT,
                                              unsigned short* __restrict__ ctx) {
    __shared__ float lbias[4096];
    __shared__ float mrg[2][64][19];
    const int wg = blockIdx.x;
    const int bh = wg >> 6, qb32 = wg & 63;
    const int b = bh >> 3, h = bh & 7;
    const int tid = threadIdx.x;
    const int wvv = tid >> 6, lane = tid & 63;
    const int qsub = wvv & 1, khalf = wvv >> 1;
    const int g = lane >> 4, qi = lane & 15;

    for (int i = tid; i < 4095; i += 256) lbias[i] = biasT[h * 4096 + i];
    __syncthreads();

    const int q = qb32 * 32 + qsub * 16 + qi;             // this lane's q row
    const long rowQ = (long)(b * 2048 + q) * 512 + h * 64;
    short8 qh[2], ql[2];
    #pragma unroll
    for (int dc = 0; dc < 2; ++dc) {
        int off = dc * 32 + g * 8;
        qh[dc] = *reinterpret_cast<const short8*>(qhi + rowQ + off);
        ql[dc] = *reinterpret_cast<const short8*>(qlo + rowQ + off);
    }
    const long kbase = (long)(b * 2048) * 512 + h * 64;
    const long vbase = (long)((b * 8 + h) * 64) * 2048;

    f32x4 zf = {0.f, 0.f, 0.f, 0.f};
    f32x4 oacc[4] = {zf, zf, zf, zf};
    float m_run = -__builtin_inff(), l_run = 0.f;
    const int kbeg = khalf * 1024;

    for (int k0 = kbeg; k0 < kbeg + 1024; k0 += 32) {
        short8 akh[2][2], akl[2][2];
        #pragma unroll
        for (int t2 = 0; t2 < 2; ++t2)
            #pragma unroll
            for (int dc = 0; dc < 2; ++dc) {
                long a = kbase + (long)(k0 + t2 * 16 + qi) * 512 + dc * 32 + g * 8;
                akh[t2][dc] = *reinterpret_cast<const short8*>(khi + a);
                akl[t2][dc] = *reinterpret_cast<const short8*>(klo + a);
            }
        f32x4 st[2] = {zf, zf};
        #pragma unroll
        for (int t2 = 0; t2 < 2; ++t2)
            #pragma unroll
            for (int dc = 0; dc < 2; ++dc) {
                st[t2] = MFMA16(akh[t2][dc], qh[dc], st[t2]);
                st[t2] = MFMA16(akh[t2][dc], ql[dc], st[t2]);
                st[t2] = MFMA16(akl[t2][dc], qh[dc], st[t2]);
            }
        // bias + online softmax (scores for this lane: k = k0 + 16*t2 + 4*g + r)
        float s8[8];
        #pragma unroll
        for (int t2 = 0; t2 < 2; ++t2)
            #pragma unroll
            for (int r = 0; r < 4; ++r) {
                int kk = k0 + t2 * 16 + g * 4 + r;
                s8[t2 * 4 + r] = st[t2][r] + lbias[kk - q + 2047];
            }
        float mx = s8[0];
        #pragma unroll
        for (int i = 1; i < 8; ++i) mx = fmaxf(mx, s8[i]);
        mx = fmaxf(mx, __shfl_xor(mx, 16));
        mx = fmaxf(mx, __shfl_xor(mx, 32));
        float mnew = fmaxf(m_run, mx);
        float scale = __expf(m_run - mnew);
        float psum = 0.f;
        unsigned pu[4];
        #pragma unroll
        for (int t2 = 0; t2 < 2; ++t2) {
            float p0 = __expf(s8[t2 * 4 + 0] - mnew);
            float p1 = __expf(s8[t2 * 4 + 1] - mnew);
            float p2 = __expf(s8[t2 * 4 + 2] - mnew);
            float p3 = __expf(s8[t2 * 4 + 3] - mnew);
            unsigned short b0 = f2bf(p0), b1 = f2bf(p1), b2 = f2bf(p2), b3v = f2bf(p3);
            // denominator from the SAME rounded weights PV will use
            psum += bf2f(b0) + bf2f(b1) + bf2f(b2) + bf2f(b3v);
            pu[t2 * 2 + 0] = (unsigned)b0 | ((unsigned)b1 << 16);
            pu[t2 * 2 + 1] = (unsigned)b2 | ((unsigned)b3v << 16);
        }
        l_run = l_run * scale + psum;
        m_run = mnew;
        #pragma unroll
        for (int dt = 0; dt < 4; ++dt) {
            oacc[dt][0] *= scale; oacc[dt][1] *= scale;
            oacc[dt][2] *= scale; oacc[dt][3] *= scale;
        }
        // exchange p -> PV B-fragment: target group g needs k in [8g, 8g+8)
        uint4v pf;
        const int t_sel = g >> 1, b3 = g & 1;
        #pragma unroll
        for (int c = 0; c < 4; ++c) {
            int gp = 2 * b3 + (c >> 1);
            int srcLane = qi | (gp << 4);
            unsigned y0 = __shfl(pu[c & 1], srcLane);
            unsigned y1 = __shfl(pu[2 + (c & 1)], srcLane);
            pf[c] = t_sel ? y1 : y0;
        }
        short8 pfrag = __builtin_bit_cast(short8, pf);
        // PV: oaccT[d][q] += V^T(16d x 32k) * P^T(32k x 16q)
        #pragma unroll
        for (int dt = 0; dt < 4; ++dt) {
            short8 vf = *reinterpret_cast<const short8*>(
                vT + vbase + (long)(dt * 16 + qi) * 2048 + k0 + g * 8);
            oacc[dt] = MFMA16(vf, pfrag, oacc[dt]);
        }
    }

    // merge the two k-halves (waves 2,3 publish; waves 0,1 combine + write)
    if (khalf == 1) {
        float* mp = &mrg[qsub][lane][0];
        mp[0] = m_run; mp[1] = l_run;
        #pragma unroll
        for (int dt = 0; dt < 4; ++dt)
            #pragma unroll
            for (int r = 0; r < 4; ++r) mp[2 + dt * 4 + r] = oacc[dt][r];
    }
    __syncthreads();
    if (khalf == 0) {
        const float* mp = &mrg[qsub][lane][0];
        float m2 = mp[0], l2 = mp[1];
        float mstar = fmaxf(m_run, m2);
        float a1 = __expf(m_run - mstar);
        float a2 = __expf(m2 - mstar);
        float lt = l_run * a1 + l2 * a2;
        lt += __shfl_xor(lt, 16);
        lt += __shfl_xor(lt, 32);
        float inv = 1.0f / lt;
        const long crow = (long)(b * 2048 + q) * 512 + h * 64;
        #pragma unroll
        for (int dt = 0; dt < 4; ++dt) {
            us4 w;
            #pragma unroll
            for (int r = 0; r < 4; ++r)
                w[r] = f2bf((oacc[dt][r] * a1 + mp[2 + dt * 4 + r] * a2) * inv);
            *reinterpret_cast<us4*>(ctx + crow + dt * 16 + g * 4) = w;
        }
    }
}

// ---------- output projection: ctx[4096x512] @ Wo -> d_out (f32) ----------
__global__ __launch_bounds__(256) void k_oproj(const unsigned short* __restrict__ ctx,
                                               const unsigned short* __restrict__ wot,
                                               float* __restrict__ outp) {
    const int wgid = blockIdx.x;            // 128 = 32 mt * 4 nt
    const int nt = wgid & 3, mt = wgid >> 2;
    const int tid = threadIdx.x, wv = tid >> 6, lane = tid & 63;
    const int wr = wv >> 1, wc = wv & 1;
    const int g = lane >> 4, li = lane & 15;
    const int m0 = mt * 128 + wr * 64;
    const int n0 = nt * 128 + wc * 64;

    f32x4 zf = {0.f, 0.f, 0.f, 0.f};
    f32x4 acc[4][4];
    #pragma unroll
    for (int i = 0; i < 4; ++i)
        #pragma unroll
        for (int j = 0; j < 4; ++j) acc[i][j] = zf;

    for (int ks = 0; ks < 512; ks += 32) {
        int koff = ks + g * 8;
        short8 af[4], bf[4];
        #pragma unroll
        for (int i = 0; i < 4; ++i) {
            af[i] = *reinterpret_cast<const short8*>(ctx + (long)(m0 + i * 16 + li) * 512 + koff);
            bf[i] = *reinterpret_cast<const short8*>(wot + (long)(n0 + i * 16 + li) * 512 + koff);
        }
        #pragma unroll
        for (int i = 0; i < 4; ++i)
            #pragma unroll
            for (int j = 0; j < 4; ++j)
                acc[i][j] = MFMA16(af[i], bf[j], acc[i][j]);
    }
    #pragma unroll
    for (int i = 0; i < 4; ++i) {
        int rowb = m0 + i * 16 + g * 4;
        #pragma unroll
        for (int j = 0; j < 4; ++j) {
            int col = n0 + j * 16 + li;
            #pragma unroll
            for (int r = 0; r < 4; ++r)
                outp[(long)(rowb + r) * 512 + col] = acc[i][j][r];
        }
    }
}

// ---------- position_bias writer: [8][2048][2048] f32 ----------
__global__ __launch_bounds__(256) void k_biasout(const float* __restrict__ biasT,
                                                 float* __restrict__ outb) {
    long t = (long)blockIdx.x * 256 + threadIdx.x;   // 4,194,304 threads, 8 elems each
    int h = (int)(t >> 19);
    long r = t & 524287;
    int qq = (int)(r >> 8);
    int k8 = (int)(r & 255) * 8;
    const float* src = biasT + h * 4096 + (k8 - qq + 2047);
    f32x8 w;
    #pragma unroll
    for (int i = 0; i < 8; ++i) w[i] = src[i];
    *reinterpret_cast<f32x8*>(outb + t * 8) = w;
}

// ---------- launch ----------
extern "C" void kernel_launch(void* const* d_in, const int* in_sizes, int n_in,
                              void* d_out, int out_size, void* d_ws, size_t ws_size,
                              hipStream_t stream) {
    const float* hidden = (const float*)d_in[0];
    const float* Wq = (const float*)d_in[1];
    const float* Wk = (const float*)d_in[2];
    const float* Wv = (const float*)d_in[3];
    const float* Wo = (const float*)d_in[4];
    const float* emb = (const float*)d_in[5];
    float* out = (float*)d_out;

    char* ws = (char*)d_ws;
    size_t off = 0;
    auto alloc = [&](size_t bytes) { char* p = ws + off; off += (bytes + 255) & ~(size_t)255; return p; };

    unsigned short* hid_hi = (unsigned short*)alloc(4096ull * 512 * 2);
    unsigned short* hid_lo = (unsigned short*)alloc(4096ull * 512 * 2);
    unsigned short* wqthi  = (unsigned short*)alloc(512ull * 512 * 2);
    unsigned short* wqtlo  = (unsigned short*)alloc(512ull * 512 * 2);
    unsigned short* wkthi  = (unsigned short*)alloc(512ull * 512 * 2);
    unsigned short* wktlo  = (unsigned short*)alloc(512ull * 512 * 2);
    unsigned short* wvt    = (unsigned short*)alloc(512ull * 512 * 2);
    unsigned short* wot    = (unsigned short*)alloc(512ull * 512 * 2);
    float*          biasT  = (float*)alloc(8ull * 4096 * 4);
    unsigned short* q_hi   = (unsigned short*)alloc(4096ull * 512 * 2);
    unsigned short* q_lo   = (unsigned short*)alloc(4096ull * 512 * 2);
    unsigned short* k_hi   = (unsigned short*)alloc(4096ull * 512 * 2);
    unsigned short* k_lo   = (unsigned short*)alloc(4096ull * 512 * 2);
    unsigned short* vT     = (unsigned short*)alloc(4096ull * 512 * 2);
    unsigned short* ctx    = (unsigned short*)alloc(4096ull * 512 * 2);

    k_prep_hidden<<<2048, 256, 0, stream>>>(hidden, hid_hi, hid_lo);
    k_prep_w<<<4096, 256, 0, stream>>>(Wq, Wk, Wv, Wo, wqthi, wqtlo, wkthi, wktlo, wvt, wot);
    k_prep_bias<<<128, 256, 0, stream>>>(emb, biasT);
    k_proj<<<384, 256, 0, stream>>>(hid_hi, hid_lo, wqthi, wqtlo, wkthi, wktlo, wvt,
                                    q_hi, q_lo, k_hi, k_lo, vT);
    k_attn<<<1024, 256, 0, stream>>>(q_hi, q_lo, k_hi, k_lo, vT, biasT, ctx);
    k_oproj<<<128, 256, 0, stream>>>(ctx, wot, out);
    k_biasout<<<16384, 256, 0, stream>>>(biasT, out + 2097152);
}

// Round 5
// 215.758 us; speedup vs baseline: 1.4022x; 1.4022x over previous
//
#include <hip/hip_runtime.h>

typedef __attribute__((ext_vector_type(8))) short short8;
typedef __attribute__((ext_vector_type(4))) float f32x4;
typedef __attribute__((ext_vector_type(16))) float f32x16;
typedef __attribute__((ext_vector_type(4))) float float4v;
typedef __attribute__((ext_vector_type(8))) float f32x8;
typedef __attribute__((ext_vector_type(4))) unsigned short us4;
typedef __attribute__((ext_vector_type(8))) unsigned short us8v;
typedef __attribute__((ext_vector_type(4))) unsigned int uint4v;

#define DEVI __device__ __forceinline__
#define MFMA16(a,b,c) __builtin_amdgcn_mfma_f32_16x16x32_bf16((a),(b),(c),0,0,0)
#define MFMA32(a,b,c) __builtin_amdgcn_mfma_f32_32x32x16_bf16((a),(b),(c),0,0,0)

// ---------- helpers ----------
DEVI unsigned short f2bf(float x) {            // f32 -> bf16 bits, RNE
    unsigned u = __builtin_bit_cast(unsigned, x);
    u += 0x7FFFu + ((u >> 16) & 1u);
    return (unsigned short)(u >> 16);
}
DEVI float bf2f(unsigned short b) {
    return __builtin_bit_cast(float, ((unsigned)b) << 16);
}

// ---------- prep: split hidden f32 -> bf16 hi/lo ----------
__global__ __launch_bounds__(256) void k_prep_hidden(const float* __restrict__ hid,
                                                     unsigned short* __restrict__ hh,
                                                     unsigned short* __restrict__ hl) {
    int i = blockIdx.x * 256 + threadIdx.x;     // 524288 threads, 4 f32 each
    float4v v = *reinterpret_cast<const float4v*>(hid + (long)i * 4);
    us4 a, b;
    #pragma unroll
    for (int j = 0; j < 4; ++j) {
        float x = v[j];
        unsigned short h = f2bf(x);
        a[j] = h;
        b[j] = f2bf(x - bf2f(h));
    }
    *reinterpret_cast<us4*>(hh + (long)i * 4) = a;
    *reinterpret_cast<us4*>(hl + (long)i * 4) = b;
}

// ---------- prep: LDS-tiled transpose of weights, split Wq/Wk ----------
__global__ __launch_bounds__(256) void k_prep_w(const float* __restrict__ wq, const float* __restrict__ wk,
                                                const float* __restrict__ wvp, const float* __restrict__ wo,
                                                unsigned short* __restrict__ wqthi, unsigned short* __restrict__ wqtlo,
                                                unsigned short* __restrict__ wkthi, unsigned short* __restrict__ wktlo,
                                                unsigned short* __restrict__ wvt, unsigned short* __restrict__ wot) {
    __shared__ float tile[64][65];
    const int bid = blockIdx.x;                 // 256 = 4 mats x 64 tiles
    const int mat = bid >> 6, t6 = bid & 63;
    const int tr = t6 >> 3, tc = t6 & 7;        // source tile coords: [k-tile][n-tile]
    const float* src = mat == 0 ? wq : mat == 1 ? wk : mat == 2 ? wvp : wo;
    const int t = threadIdx.x;
    const int r = t >> 2, cc = (t & 3) << 4;
    const float* sp = src + (long)(tr * 64 + r) * 512 + tc * 64 + cc;
    #pragma unroll
    for (int j = 0; j < 16; j += 4) {
        float4v v = *reinterpret_cast<const float4v*>(sp + j);
        tile[r][cc + j + 0] = v[0];
        tile[r][cc + j + 1] = v[1];
        tile[r][cc + j + 2] = v[2];
        tile[r][cc + j + 3] = v[3];
    }
    __syncthreads();
    // out[n][k]: n = tc*64 + r ; k = tr*64 + cc + j
    const long obase = (long)(tc * 64 + r) * 512 + tr * 64 + cc;
    us8v h0, h1, l0, l1;
    #pragma unroll
    for (int j = 0; j < 8; ++j) {
        float x = tile[cc + j][r];
        unsigned short hb = f2bf(x);
        h0[j] = hb; l0[j] = f2bf(x - bf2f(hb));
        float y = tile[cc + 8 + j][r];
        unsigned short hb2 = f2bf(y);
        h1[j] = hb2; l1[j] = f2bf(y - bf2f(hb2));
    }
    if (mat <= 1) {
        unsigned short* oh = mat ? wkthi : wqthi;
        unsigned short* ol = mat ? wktlo : wqtlo;
        *reinterpret_cast<us8v*>(oh + obase) = h0;
        *reinterpret_cast<us8v*>(oh + obase + 8) = h1;
        *reinterpret_cast<us8v*>(ol + obase) = l0;
        *reinterpret_cast<us8v*>(ol + obase + 8) = l1;
    } else {
        unsigned short* oh = mat == 2 ? wvt : wot;
        *reinterpret_cast<us8v*>(oh + obase) = h0;
        *reinterpret_cast<us8v*>(oh + obase + 8) = h1;
    }
}

// ---------- prep: bias table biasT[h][rel+2047] ----------
DEVI int bucket_large(int a) {   // exact integer thresholds of 8+floor(2*log2(a/8)), clamp 15
    if (a < 12) return 8;
    if (a < 16) return 9;
    if (a < 23) return 10;
    if (a < 32) return 11;
    if (a < 46) return 12;
    if (a < 64) return 13;
    if (a < 91) return 14;
    return 15;
}
__global__ __launch_bounds__(256) void k_prep_bias(const float* __restrict__ emb, float* __restrict__ biasT) {
    int t = blockIdx.x * 256 + threadIdx.x;
    if (t >= 8 * 4095) return;
    int h = t / 4095;
    int idx = t - h * 4095;
    int rel = idx - 2047;                // rel = k - q
    int a = rel < 0 ? -rel : rel;
    int bucket = (rel > 0 ? 16 : 0) + (a < 8 ? a : bucket_large(a));
    biasT[h * 4096 + idx] = emb[bucket * 8 + h];
}

// ---------- fused QKV projection (R2-proven) ----------
__global__ __launch_bounds__(256) void k_proj(const unsigned short* __restrict__ hh,
                                              const unsigned short* __restrict__ hl,
                                              const unsigned short* __restrict__ wqthi, const unsigned short* __restrict__ wqtlo,
                                              const unsigned short* __restrict__ wkthi, const unsigned short* __restrict__ wktlo,
                                              const unsigned short* __restrict__ wvt,
                                              unsigned short* __restrict__ q_hi, unsigned short* __restrict__ q_lo,
                                              unsigned short* __restrict__ k_hi, unsigned short* __restrict__ k_lo,
                                              unsigned short* __restrict__ vT) {
    const int wgid = blockIdx.x;            // 384 = 32 mt * 12 nt
    const int nt = wgid % 12, mt = wgid / 12;
    const int sec = nt >> 2;                // 0:Q 1:K 2:V
    const bool isv = (sec == 2);
    const int tid = threadIdx.x, wv = tid >> 6, lane = tid & 63;
    const int wr = wv >> 1, wc = wv & 1;
    const int g = lane >> 4, li = lane & 15;
    const int m0 = mt * 128 + wr * 64;
    const int n0 = (nt & 3) * 128 + wc * 64;    // col within section [0,512)
    const unsigned short* bh_ = (sec == 0) ? wqthi : (sec == 1) ? wkthi : wvt;
    const unsigned short* bl_ = (sec == 0) ? wqtlo : wktlo;

    f32x4 zf = {0.f, 0.f, 0.f, 0.f};
    f32x4 acc[4][4];
    #pragma unroll
    for (int i = 0; i < 4; ++i)
        #pragma unroll
        for (int j = 0; j < 4; ++j) acc[i][j] = zf;

    for (int ks = 0; ks < 512; ks += 32) {
        int koff = ks + g * 8;
        short8 ah[4], al[4], bhf[4], blf[4];
        #pragma unroll
        for (int i = 0; i < 4; ++i) {
            long ar = (long)(m0 + i * 16 + li) * 512 + koff;
            ah[i] = *reinterpret_cast<const short8*>(hh + ar);
            if (!isv) al[i] = *reinterpret_cast<const short8*>(hl + ar);
            long br = (long)(n0 + i * 16 + li) * 512 + koff;
            bhf[i] = *reinterpret_cast<const short8*>(bh_ + br);
            if (!isv) blf[i] = *reinterpret_cast<const short8*>(bl_ + br);
        }
        #pragma unroll
        for (int i = 0; i < 4; ++i)
            #pragma unroll
            for (int j = 0; j < 4; ++j) {
                acc[i][j] = MFMA16(ah[i], bhf[j], acc[i][j]);
                if (!isv) {
                    acc[i][j] = MFMA16(ah[i], blf[j], acc[i][j]);
                    acc[i][j] = MFMA16(al[i], bhf[j], acc[i][j]);
                }
            }
    }

    if (!isv) {
        unsigned short* ohi = (sec == 0) ? q_hi : k_hi;
        unsigned short* olo = (sec == 0) ? q_lo : k_lo;
        #pragma unroll
        for (int i = 0; i < 4; ++i) {
            int rowb = m0 + i * 16 + g * 4;
            #pragma unroll
            for (int j = 0; j < 4; ++j) {
                int col = n0 + j * 16 + li;
                #pragma unroll
                for (int r = 0; r < 4; ++r) {
                    float x = acc[i][j][r];
                    unsigned short hb = f2bf(x);
                    long o = (long)(rowb + r) * 512 + col;
                    ohi[o] = hb;
                    olo[o] = f2bf(x - bf2f(hb));
                }
            }
        }
    } else {
        #pragma unroll
        for (int i = 0; i < 4; ++i) {
            int rowb = m0 + i * 16 + g * 4;      // 4 consecutive s
            int bb = rowb >> 11, ss = rowb & 2047;
            #pragma unroll
            for (int j = 0; j < 4; ++j) {
                int nv = n0 + j * 16 + li;       // [0,512)
                int hh2 = nv >> 6, dd = nv & 63;
                us4 w;
                #pragma unroll
                for (int r = 0; r < 4; ++r) w[r] = f2bf(acc[i][j][r]);
                *reinterpret_cast<us4*>(vT + ((long)((bb * 8 + hh2) * 64 + dd)) * 2048 + ss) = w;
            }
        }
    }
}

// ---------- flash attention: 32x32 swapped-QK^T, lane-local row softmax ----------
// grid 1024 = 16 bh * 64 q-tiles(32 rows). block 128 = 2 waves: kh = k-half.
// SS = mfma32(K,Q): lane: q = lane&31, k_loc(r) = (r&3)+8*(r>>2)+4*hi.
__global__ __launch_bounds__(128) void k_attn(const unsigned short* __restrict__ qhi,
                                              const unsigned short* __restrict__ qlo,
                                              const unsigned short* __restrict__ khi,
                                              const unsigned short* __restrict__ klo,
                                              const unsigned short* __restrict__ vT,
                                              const float* __restrict__ biasT,
                                              unsigned short* __restrict__ ctx) {
    __shared__ float lb[2080];
    __shared__ float mrg[64][34];
    const int wg = blockIdx.x;
    const int bh = wg >> 6, qt = wg & 63;
    const int b = bh >> 3, h = bh & 7;
    const int tid = threadIdx.x;
    const int kh = tid >> 6, lane = tid & 63;
    const int ql_ = lane & 31, hi = lane >> 5;
    const int q0 = qt * 32;

    // bias window: lb[i] = biasT[h][2016 - q0 + i]; in-loop index = k - ql_ + 31
    for (int i = tid; i < 2080; i += 128) lb[i] = biasT[h * 4096 + (2016 - q0) + i];
    __syncthreads();

    const int q = q0 + ql_;
    const long rowQ = (long)(b * 2048 + q) * 512 + h * 64 + hi * 8;
    short8 qfh[4], qfl[4];
    #pragma unroll
    for (int ds = 0; ds < 4; ++ds) {
        qfh[ds] = *reinterpret_cast<const short8*>(qhi + rowQ + ds * 16);
        qfl[ds] = *reinterpret_cast<const short8*>(qlo + rowQ + ds * 16);
    }
    const int kbeg = kh * 1024;
    const long krow = (long)(b * 2048 + kbeg + ql_) * 512 + h * 64 + hi * 8;
    const unsigned short* kph = khi + krow;
    const unsigned short* kpl = klo + krow;
    const unsigned short* vp0 = vT + (long)((b * 8 + h) * 64 + ql_) * 2048 + kbeg + hi * 8;
    const unsigned short* vp1 = vp0 + 32 * 2048;

    f32x16 o0, o1;
    #pragma unroll
    for (int i = 0; i < 16; ++i) { o0[i] = 0.f; o1[i] = 0.f; }
    float m_run = -__builtin_inff(), l_run = 0.f;

    for (int it = 0; it < 32; ++it) {
        const int k0 = kbeg + it * 32;
        short8 akh[4], akl[4];
        #pragma unroll
        for (int ds = 0; ds < 4; ++ds) {
            akh[ds] = *reinterpret_cast<const short8*>(kph + ds * 16);
            akl[ds] = *reinterpret_cast<const short8*>(kpl + ds * 16);
        }
        f32x16 ss;
        #pragma unroll
        for (int i = 0; i < 16; ++i) ss[i] = 0.f;
        #pragma unroll
        for (int ds = 0; ds < 4; ++ds) {
            ss = MFMA32(akh[ds], qfh[ds], ss);
            ss = MFMA32(akh[ds], qfl[ds], ss);
            ss = MFMA32(akl[ds], qfh[ds], ss);
        }
        // bias + row softmax (row = q, all in-lane except one hi-swap)
        const int ib = k0 - ql_ + 31 + 4 * hi;
        float s[16];
        #pragma unroll
        for (int r = 0; r < 16; ++r)
            s[r] = ss[r] + lb[ib + (r & 3) + 8 * (r >> 2)];
        float mx = s[0];
        #pragma unroll
        for (int r = 1; r < 16; ++r) mx = fmaxf(mx, s[r]);
        mx = fmaxf(mx, __shfl_xor(mx, 32));
        float mnew = fmaxf(m_run, mx);
        float scale = __expf(m_run - mnew);
        float p[16];
        #pragma unroll
        for (int r = 0; r < 16; ++r) p[r] = __expf(s[r] - mnew);
        unsigned W[8];
        float psum = 0.f;
        #pragma unroll
        for (int r2 = 0; r2 < 8; ++r2) {
            unsigned short b0 = f2bf(p[2 * r2]), b1 = f2bf(p[2 * r2 + 1]);
            psum += bf2f(b0) + bf2f(b1);          // denominator from rounded weights
            W[r2] = (unsigned)b0 | ((unsigned)b1 << 16);
        }
        l_run = l_run * scale + psum;
        m_run = mnew;
        #pragma unroll
        for (int i = 0; i < 16; ++i) { o0[i] *= scale; o1[i] *= scale; }
        unsigned Sw[8];
        #pragma unroll
        for (int r2 = 0; r2 < 8; ++r2) Sw[r2] = __shfl_xor(W[r2], 32);
        #pragma unroll
        for (int t = 0; t < 2; ++t) {
            uint4v bw;
            bw[0] = hi ? Sw[4 * t + 2] : W[4 * t + 0];
            bw[1] = hi ? Sw[4 * t + 3] : W[4 * t + 1];
            bw[2] = hi ? W[4 * t + 2] : Sw[4 * t + 0];
            bw[3] = hi ? W[4 * t + 3] : Sw[4 * t + 1];
            short8 pf = __builtin_bit_cast(short8, bw);
            short8 v0 = *reinterpret_cast<const short8*>(vp0 + it * 32 + t * 16);
            short8 v1 = *reinterpret_cast<const short8*>(vp1 + it * 32 + t * 16);
            o0 = MFMA32(v0, pf, o0);
            o1 = MFMA32(v1, pf, o1);
        }
        kph += 32 * 512;
        kpl += 32 * 512;
    }

    // merge the two k-halves
    if (kh == 1) {
        float* mp = &mrg[lane][0];
        mp[0] = m_run; mp[1] = l_run;
        #pragma unroll
        for (int i = 0; i < 16; ++i) { mp[2 + i] = o0[i]; mp[18 + i] = o1[i]; }
    }
    __syncthreads();
    if (kh == 0) {
        const float* mp = &mrg[lane][0];
        float m2 = mp[0], l2 = mp[1];
        float ms = fmaxf(m_run, m2);
        float a1 = __expf(m_run - ms);
        float a2 = __expf(m2 - ms);
        float lt = l_run * a1 + l2 * a2;
        lt += __shfl_xor(lt, 32);
        float inv = 1.0f / lt;
        const long crow = (long)(b * 2048 + q) * 512 + h * 64;
        #pragma unroll
        for (int a = 0; a < 4; ++a) {
            us4 w0, w1;
            #pragma unroll
            for (int c = 0; c < 4; ++c) {
                w0[c] = f2bf((o0[4 * a + c] * a1 + mp[2 + 4 * a + c] * a2) * inv);
                w1[c] = f2bf((o1[4 * a + c] * a1 + mp[18 + 4 * a + c] * a2) * inv);
            }
            *reinterpret_cast<us4*>(ctx + crow + 8 * a + 4 * hi) = w0;
            *reinterpret_cast<us4*>(ctx + crow + 32 + 8 * a + 4 * hi) = w1;
        }
    }
}

// ---------- output projection: ctx[4096x512] @ Wo -> d_out (f32) ----------
__global__ __launch_bounds__(256) void k_oproj(const unsigned short* __restrict__ ctx,
                                               const unsigned short* __restrict__ wot,
                                               float* __restrict__ outp) {
    const int wgid = blockIdx.x;            // 128 = 32 mt * 4 nt
    const int nt = wgid & 3, mt = wgid >> 2;
    const int tid = threadIdx.x, wv = tid >> 6, lane = tid & 63;
    const int wr = wv >> 1, wc = wv & 1;
    const int g = lane >> 4, li = lane & 15;
    const int m0 = mt * 128 + wr * 64;
    const int n0 = nt * 128 + wc * 64;

    f32x4 zf = {0.f, 0.f, 0.f, 0.f};
    f32x4 acc[4][4];
    #pragma unroll
    for (int i = 0; i < 4; ++i)
        #pragma unroll
        for (int j = 0; j < 4; ++j) acc[i][j] = zf;

    for (int ks = 0; ks < 512; ks += 32) {
        int koff = ks + g * 8;
        short8 af[4], bf[4];
        #pragma unroll
        for (int i = 0; i < 4; ++i) {
            af[i] = *reinterpret_cast<const short8*>(ctx + (long)(m0 + i * 16 + li) * 512 + koff);
            bf[i] = *reinterpret_cast<const short8*>(wot + (long)(n0 + i * 16 + li) * 512 + koff);
        }
        #pragma unroll
        for (int i = 0; i < 4; ++i)
            #pragma unroll
            for (int j = 0; j < 4; ++j)
                acc[i][j] = MFMA16(af[i], bf[j], acc[i][j]);
    }
    #pragma unroll
    for (int i = 0; i < 4; ++i) {
        int rowb = m0 + i * 16 + g * 4;
        #pragma unroll
        for (int j = 0; j < 4; ++j) {
            int col = n0 + j * 16 + li;
            #pragma unroll
            for (int r = 0; r < 4; ++r)
                outp[(long)(rowb + r) * 512 + col] = acc[i][j][r];
        }
    }
}

// ---------- position_bias writer: [8][2048][2048] f32 ----------
__global__ __launch_bounds__(256) void k_biasout(const float* __restrict__ biasT,
                                                 float* __restrict__ outb) {
    long t = (long)blockIdx.x * 256 + threadIdx.x;   // 4,194,304 threads, 8 elems each
    int h = (int)(t >> 19);
    long r = t & 524287;
    int qq = (int)(r >> 8);
    int k8 = (int)(r & 255) * 8;
    const float* src = biasT + h * 4096 + (k8 - qq + 2047);
    f32x8 w;
    #pragma unroll
    for (int i = 0; i < 8; ++i) w[i] = src[i];
    *reinterpret_cast<f32x8*>(outb + t * 8) = w;
}

// ---------- launch ----------
extern "C" void kernel_launch(void* const* d_in, const int* in_sizes, int n_in,
                              void* d_out, int out_size, void* d_ws, size_t ws_size,
                              hipStream_t stream) {
    const float* hidden = (const float*)d_in[0];
    const float* Wq = (const float*)d_in[1];
    const float* Wk = (const float*)d_in[2];
    const float* Wv = (const float*)d_in[3];
    const float* Wo = (const float*)d_in[4];
    const float* emb = (const float*)d_in[5];
    float* out = (float*)d_out;

    char* ws = (char*)d_ws;
    size_t off = 0;
    auto alloc = [&](size_t bytes) { char* p = ws + off; off += (bytes + 255) & ~(size_t)255; return p; };

    unsigned short* hid_hi = (unsigned short*)alloc(4096ull * 512 * 2);
    unsigned short* hid_lo = (unsigned short*)alloc(4096ull * 512 * 2);
    unsigned short* wqthi  = (unsigned short*)alloc(512ull * 512 * 2);
    unsigned short* wqtlo  = (unsigned short*)alloc(512ull * 512 * 2);
    unsigned short* wkthi  = (unsigned short*)alloc(512ull * 512 * 2);
    unsigned short* wktlo  = (unsigned short*)alloc(512ull * 512 * 2);
    unsigned short* wvt    = (unsigned short*)alloc(512ull * 512 * 2);
    unsigned short* wot    = (unsigned short*)alloc(512ull * 512 * 2);
    float*          biasT  = (float*)alloc(8ull * 4096 * 4);
    unsigned short* q_hi   = (unsigned short*)alloc(4096ull * 512 * 2);
    unsigned short* q_lo   = (unsigned short*)alloc(4096ull * 512 * 2);
    unsigned short* k_hi   = (unsigned short*)alloc(4096ull * 512 * 2);
    unsigned short* k_lo   = (unsigned short*)alloc(4096ull * 512 * 2);
    unsigned short* vT     = (unsigned short*)alloc(4096ull * 512 * 2);
    unsigned short* ctx    = (unsigned short*)alloc(4096ull * 512 * 2);

    k_prep_hidden<<<2048, 256, 0, stream>>>(hidden, hid_hi, hid_lo);
    k_prep_w<<<256, 256, 0, stream>>>(Wq, Wk, Wv, Wo, wqthi, wqtlo, wkthi, wktlo, wvt, wot);
    k_prep_bias<<<128, 256, 0, stream>>>(emb, biasT);
    k_proj<<<384, 256, 0, stream>>>(hid_hi, hid_lo, wqthi, wqtlo, wkthi, wktlo, wvt,
                                    q_hi, q_lo, k_hi, k_lo, vT);
    k_attn<<<1024, 128, 0, stream>>>(q_hi, q_lo, k_hi, k_lo, vT, biasT, ctx);
    k_oproj<<<128, 256, 0, stream>>>(ctx, wot, out);
    k_biasout<<<16384, 256, 0, stream>>>(biasT, out + 2097152);
}